// Round 1
// baseline (932.674 us; speedup 1.0000x reference)
//
#include <hip/hip_runtime.h>
#include <cstdint>
#include <cstddef>

#define D_MODEL 1024
#define D_FF 4096
#define NUM_EXPERTS 6
#define FIXED_EXPERTS 2
#define NTOK 4096
#define LN_EPS 1e-5f

typedef __bf16 bf16x8 __attribute__((ext_vector_type(8)));
typedef float f32x4 __attribute__((ext_vector_type(4)));
typedef unsigned short u16x4 __attribute__((ext_vector_type(4)));
typedef unsigned short u16x8 __attribute__((ext_vector_type(8)));

static __device__ __forceinline__ unsigned short f2bf(float f) {
    union { float f; unsigned u; } v; v.f = f;
    unsigned r = v.u + 0x7fffu + ((v.u >> 16) & 1u);
    return (unsigned short)(r >> 16);
}

// ---------------- router: logits (fp32 exact) + top-2 selection ----------------
__global__ __launch_bounds__(256) void router_kernel(
        const float* __restrict__ x, const float* __restrict__ rW,
        float* __restrict__ logits, int* __restrict__ sel) {
    int wid = threadIdx.x >> 6, lane = threadIdx.x & 63;
    int t = blockIdx.x * 4 + wid;
    const float* xr = x + (size_t)t * D_MODEL;
    float a0 = 0.f, a1 = 0.f, a2 = 0.f, a3 = 0.f;
    for (int d = lane; d < D_MODEL; d += 64) {
        float xv = xr[d];
        const float* w = rW + d * 4;
        a0 += xv * w[0]; a1 += xv * w[1]; a2 += xv * w[2]; a3 += xv * w[3];
    }
    #pragma unroll
    for (int off = 32; off; off >>= 1) {
        a0 += __shfl_xor(a0, off); a1 += __shfl_xor(a1, off);
        a2 += __shfl_xor(a2, off); a3 += __shfl_xor(a3, off);
    }
    if (lane == 0) {
        float l[4] = {a0, a1, a2, a3};
        logits[t * 4 + 0] = a0; logits[t * 4 + 1] = a1;
        logits[t * 4 + 2] = a2; logits[t * 4 + 3] = a3;
        int e0 = 0; float b = l[0];
        #pragma unroll
        for (int e = 1; e < 4; ++e) if (l[e] > b) { b = l[e]; e0 = e; }
        int e1 = -1; float b2 = -1e30f;
        #pragma unroll
        for (int e = 0; e < 4; ++e) {
            if (e == e0) continue;
            if (l[e] > b2) { b2 = l[e]; e1 = e; }
        }
        sel[t] = e0 | (e1 << 8);
    }
}

// ---------------- pass1: h[e] = gelu(x @ W1[e] + b1[e]), bf16 out ----------------
// grid: (BF/128, NTOK/128, 6), block 256 (4 waves, each 64x64 of the 128x128 tile)
__global__ __launch_bounds__(256) void pass1_kernel(
        const float* __restrict__ x, const float* __restrict__ W1,
        const float* __restrict__ b1, unsigned short* __restrict__ h,
        int fc, int BF) {
    __shared__ unsigned short As[128 * 64];
    __shared__ unsigned short Bs[128 * 64];
    const int e = blockIdx.z;
    const int m0 = blockIdx.y * 128;
    const int n0 = blockIdx.x * 128;      // within chunk
    const int nglob = fc + n0;            // within F
    const int tid = threadIdx.x;
    const int lane = tid & 63, wid = tid >> 6;
    const int wm = (wid >> 1) * 64, wn = (wid & 1) * 64;
    const float* W1e = W1 + (size_t)e * D_MODEL * D_FF;

    f32x4 acc[4][4];
    #pragma unroll
    for (int i = 0; i < 4; ++i)
        #pragma unroll
        for (int j = 0; j < 4; ++j) acc[i][j] = (f32x4)0.f;

    for (int kb = 0; kb < D_MODEL; kb += 64) {
        // --- stage A: x tile [128][64] f32 -> bf16, swizzled
        #pragma unroll
        for (int i = 0; i < 8; ++i) {
            int f = tid + i * 256;          // 0..2047 (float4 units)
            int row = f >> 4;
            int kp = (f & 15) << 2;
            f32x4 v = *(const f32x4*)&x[(size_t)(m0 + row) * D_MODEL + kb + kp];
            u16x4 b;
            b[0] = f2bf(v[0]); b[1] = f2bf(v[1]); b[2] = f2bf(v[2]); b[3] = f2bf(v[3]);
            *(u16x4*)&As[row * 64 + (kp ^ ((row & 7) << 3))] = b;
        }
        // --- stage B: W1 tile [64 k][128 n] f32 -> Bs[n][k] bf16, swizzled
        {
            int n = tid & 127;
            int kh = (tid >> 7) * 32;
            const float* src = &W1e[(size_t)(kb + kh) * D_FF + nglob + n];
            int swz = (n & 7) << 3;
            #pragma unroll
            for (int c = 0; c < 4; ++c) {
                u16x8 w;
                #pragma unroll
                for (int i = 0; i < 8; ++i)
                    w[i] = f2bf(src[(size_t)(c * 8 + i) * D_FF]);
                *(u16x8*)&Bs[n * 64 + ((kh + c * 8) ^ swz)] = w;
            }
        }
        __syncthreads();
        #pragma unroll
        for (int kk = 0; kk < 2; ++kk) {
            int kof = kk * 32 + (lane >> 4) * 8;
            bf16x8 a[4], b[4];
            #pragma unroll
            for (int mi = 0; mi < 4; ++mi) {
                int r = wm + mi * 16 + (lane & 15);
                a[mi] = *(const bf16x8*)&As[r * 64 + (kof ^ ((r & 7) << 3))];
            }
            #pragma unroll
            for (int ni = 0; ni < 4; ++ni) {
                int r = wn + ni * 16 + (lane & 15);
                b[ni] = *(const bf16x8*)&Bs[r * 64 + (kof ^ ((r & 7) << 3))];
            }
            #pragma unroll
            for (int mi = 0; mi < 4; ++mi)
                #pragma unroll
                for (int ni = 0; ni < 4; ++ni)
                    acc[mi][ni] = __builtin_amdgcn_mfma_f32_16x16x32_bf16(
                        a[mi], b[ni], acc[mi][ni], 0, 0, 0);
        }
        __syncthreads();
    }

    // epilogue: bias + exact gelu, store bf16
    const float* b1e = b1 + (size_t)e * D_FF + nglob;
    #pragma unroll
    for (int ni = 0; ni < 4; ++ni) {
        int col = wn + ni * 16 + (lane & 15);
        float bias = b1e[col];
        #pragma unroll
        for (int mi = 0; mi < 4; ++mi) {
            #pragma unroll
            for (int j = 0; j < 4; ++j) {
                int row = wm + mi * 16 + (lane >> 4) * 4 + j;
                float v = acc[mi][ni][j] + bias;
                float g = 0.5f * v * (1.0f + erff(v * 0.70710678118654752f));
                h[((size_t)e * NTOK + m0 + row) * BF + n0 + col] = f2bf(g);
            }
        }
    }
}

// ---------------- pass2: slot[e] (+)= h[e] @ W2[e][fc:fc+BF] (+ b2 on first) ----
// grid: (D_MODEL/128, NTOK/128, 6), block 256
__global__ __launch_bounds__(256) void pass2_kernel(
        const unsigned short* __restrict__ h, const float* __restrict__ W2,
        const float* __restrict__ b2, float* __restrict__ slot,
        int fc, int BF, int first) {
    __shared__ unsigned short As[128 * 64];
    __shared__ unsigned short Bs[128 * 64];
    const int e = blockIdx.z;
    const int m0 = blockIdx.y * 128;
    const int n0 = blockIdx.x * 128;
    const int tid = threadIdx.x;
    const int lane = tid & 63, wid = tid >> 6;
    const int wm = (wid >> 1) * 64, wn = (wid & 1) * 64;
    const unsigned short* he = h + (size_t)e * NTOK * BF;
    const float* W2e = W2 + (size_t)e * D_FF * D_MODEL;

    f32x4 acc[4][4];
    #pragma unroll
    for (int i = 0; i < 4; ++i)
        #pragma unroll
        for (int j = 0; j < 4; ++j) acc[i][j] = (f32x4)0.f;

    for (int kb = 0; kb < BF; kb += 64) {
        // --- stage A: h tile [128][64] bf16 direct, swizzled
        #pragma unroll
        for (int i = 0; i < 4; ++i) {
            int f = tid + i * 256;         // 0..1023 (u16x8 units)
            int row = f >> 3;
            int kp = (f & 7) << 3;
            u16x8 v = *(const u16x8*)&he[(size_t)(m0 + row) * BF + kb + kp];
            *(u16x8*)&As[row * 64 + (kp ^ ((row & 7) << 3))] = v;
        }
        // --- stage B: W2 tile [64 f][128 d] f32 -> Bs[n][k] bf16, swizzled
        {
            int n = tid & 127;
            int kh = (tid >> 7) * 32;
            const float* src = &W2e[(size_t)(fc + kb + kh) * D_MODEL + n0 + n];
            int swz = (n & 7) << 3;
            #pragma unroll
            for (int c = 0; c < 4; ++c) {
                u16x8 w;
                #pragma unroll
                for (int i = 0; i < 8; ++i)
                    w[i] = f2bf(src[(size_t)(c * 8 + i) * D_MODEL]);
                *(u16x8*)&Bs[n * 64 + ((kh + c * 8) ^ swz)] = w;
            }
        }
        __syncthreads();
        #pragma unroll
        for (int kk = 0; kk < 2; ++kk) {
            int kof = kk * 32 + (lane >> 4) * 8;
            bf16x8 a[4], b[4];
            #pragma unroll
            for (int mi = 0; mi < 4; ++mi) {
                int r = wm + mi * 16 + (lane & 15);
                a[mi] = *(const bf16x8*)&As[r * 64 + (kof ^ ((r & 7) << 3))];
            }
            #pragma unroll
            for (int ni = 0; ni < 4; ++ni) {
                int r = wn + ni * 16 + (lane & 15);
                b[ni] = *(const bf16x8*)&Bs[r * 64 + (kof ^ ((r & 7) << 3))];
            }
            #pragma unroll
            for (int mi = 0; mi < 4; ++mi)
                #pragma unroll
                for (int ni = 0; ni < 4; ++ni)
                    acc[mi][ni] = __builtin_amdgcn_mfma_f32_16x16x32_bf16(
                        a[mi], b[ni], acc[mi][ni], 0, 0, 0);
        }
        __syncthreads();
    }

    const float* b2e = b2 + (size_t)e * D_MODEL + n0;
    #pragma unroll
    for (int ni = 0; ni < 4; ++ni) {
        int col = wn + ni * 16 + (lane & 15);
        float bias = first ? b2e[col] : 0.f;
        #pragma unroll
        for (int mi = 0; mi < 4; ++mi) {
            #pragma unroll
            for (int j = 0; j < 4; ++j) {
                int row = wm + mi * 16 + (lane >> 4) * 4 + j;
                size_t idx = ((size_t)e * NTOK + m0 + row) * D_MODEL + n0 + col;
                float v = acc[mi][ni][j] + bias;
                if (first) slot[idx] = v;
                else       slot[idx] += v;
            }
        }
    }
}

// ---------------- pass3: gather 4 slots, /4, LayerNorm ----------------
__global__ __launch_bounds__(256) void pass3_kernel(
        const float* __restrict__ slot, const int* __restrict__ sel,
        const float* __restrict__ gamma, const float* __restrict__ beta,
        float* __restrict__ out) {
    int t = blockIdx.x;
    int s = sel[t];
    int e0 = (s & 0xff) + FIXED_EXPERTS;
    int e1 = ((s >> 8) & 0xff) + FIXED_EXPERTS;
    const float* p0 = slot + ((size_t)0 * NTOK + t) * D_MODEL;
    const float* p1 = slot + ((size_t)1 * NTOK + t) * D_MODEL;
    const float* p2 = slot + ((size_t)e0 * NTOK + t) * D_MODEL;
    const float* p3 = slot + ((size_t)e1 * NTOK + t) * D_MODEL;
    float c[4];
    float sum = 0.f, sq = 0.f;
    #pragma unroll
    for (int i = 0; i < 4; ++i) {
        int d = threadIdx.x + i * 256;
        float v = (p0[d] + p1[d] + p2[d] + p3[d]) * 0.25f;
        c[i] = v; sum += v; sq += v * v;
    }
    #pragma unroll
    for (int off = 32; off; off >>= 1) {
        sum += __shfl_xor(sum, off);
        sq  += __shfl_xor(sq, off);
    }
    __shared__ float red[8];
    int lane = threadIdx.x & 63, wid = threadIdx.x >> 6;
    if (lane == 0) { red[wid] = sum; red[4 + wid] = sq; }
    __syncthreads();
    sum = red[0] + red[1] + red[2] + red[3];
    sq  = red[4] + red[5] + red[6] + red[7];
    float mean = sum * (1.0f / 1024.0f);
    float var = sq * (1.0f / 1024.0f) - mean * mean;
    float inv = rsqrtf(var + LN_EPS);
    #pragma unroll
    for (int i = 0; i < 4; ++i) {
        int d = threadIdx.x + i * 256;
        out[(size_t)t * D_MODEL + d] = (c[i] - mean) * inv * gamma[d] + beta[d];
    }
}

extern "C" void kernel_launch(void* const* d_in, const int* in_sizes, int n_in,
                              void* d_out, int out_size, void* d_ws, size_t ws_size,
                              hipStream_t stream) {
    const float* x   = (const float*)d_in[0];
    const float* rW  = (const float*)d_in[1];
    const float* W1  = (const float*)d_in[2];
    const float* b1  = (const float*)d_in[3];
    const float* W2  = (const float*)d_in[4];
    const float* b2  = (const float*)d_in[5];
    const float* gam = (const float*)d_in[6];
    const float* bet = (const float*)d_in[7];
    float* out = (float*)d_out;
    float* logits = out + (size_t)NTOK * D_MODEL;

    char* ws = (char*)d_ws;
    int* sel = (int*)ws;
    const size_t off_h = 65536;
    const size_t slot_bytes = (size_t)NUM_EXPERTS * NTOK * D_MODEL * 4;
    int BF = 512;
    for (int cand = 4096; cand >= 512; cand >>= 1) {
        size_t need = off_h + (size_t)NUM_EXPERTS * NTOK * cand * 2 + slot_bytes;
        if (need <= ws_size) { BF = cand; break; }
    }
    unsigned short* h = (unsigned short*)(ws + off_h);
    float* slot = (float*)(ws + off_h + (size_t)NUM_EXPERTS * NTOK * (size_t)BF * 2);

    router_kernel<<<NTOK / 4, 256, 0, stream>>>(x, rW, logits, sel);
    int nch = D_FF / BF;
    for (int c = 0; c < nch; ++c) {
        pass1_kernel<<<dim3(BF / 128, NTOK / 128, NUM_EXPERTS), 256, 0, stream>>>(
            x, W1, b1, h, c * BF, BF);
        pass2_kernel<<<dim3(D_MODEL / 128, NTOK / 128, NUM_EXPERTS), 256, 0, stream>>>(
            h, W2, b2, slot, c * BF, BF, c == 0);
    }
    pass3_kernel<<<NTOK, 256, 0, stream>>>(slot, sel, gam, bet, out);
}

// Round 2
// 597.176 us; speedup vs baseline: 1.5618x; 1.5618x over previous
//
#include <hip/hip_runtime.h>
#include <cstdint>
#include <cstddef>

#define D_MODEL 1024
#define D_FF 4096
#define NTOK 4096
#define LN_EPS 1e-5f

typedef __bf16 bf16x8 __attribute__((ext_vector_type(8)));
typedef float f32x4 __attribute__((ext_vector_type(4)));
typedef unsigned short u16x4 __attribute__((ext_vector_type(4)));
typedef unsigned short u16x8 __attribute__((ext_vector_type(8)));

static __device__ __forceinline__ unsigned short f2bf(float f) {
    union { float f; unsigned u; } v; v.f = f;
    unsigned r = v.u + 0x7fffu + ((v.u >> 16) & 1u);
    return (unsigned short)(r >> 16);
}

static __device__ __forceinline__ void gload16(const void* g, void* l) {
    __builtin_amdgcn_global_load_lds(
        (const __attribute__((address_space(1))) void*)g,
        (__attribute__((address_space(3))) void*)l, 16, 0, 0);
}

// padded prefix offsets of the 4 variable experts within the row slab
static __device__ __forceinline__ void seg_of(const int* cnt, int seg[4], int pc[4]) {
    int o = 2 * NTOK;
    #pragma unroll
    for (int e = 0; e < 4; ++e) {
        int c = cnt[e * 32];
        pc[e] = (c + 127) & ~127;
        seg[e] = o;
        o += pc[e];
    }
}

// ---------------- x: f32 -> bf16 ----------------
__global__ __launch_bounds__(256) void convx_kernel(const float* __restrict__ x,
                                                    unsigned short* __restrict__ xb) {
    int idx = blockIdx.x * 256 + threadIdx.x;   // float4 units
    f32x4 v = *(const f32x4*)&x[(size_t)idx * 4];
    u16x4 b;
    b[0] = f2bf(v[0]); b[1] = f2bf(v[1]); b[2] = f2bf(v[2]); b[3] = f2bf(v[3]);
    *(u16x4*)&xb[(size_t)idx * 4] = b;
}

// ---------------- W [E][K][N] f32 -> Wt [E][N][K] bf16 ----------------
__global__ __launch_bounds__(256) void transpose_kernel(const float* __restrict__ W,
                                                        unsigned short* __restrict__ Wt,
                                                        int K, int N) {
    __shared__ unsigned short t[64][65];
    int k0 = blockIdx.y * 64, n0 = blockIdx.x * 64;
    const float* We = W + (size_t)blockIdx.z * K * N;
    unsigned short* Wte = Wt + (size_t)blockIdx.z * K * N;
    #pragma unroll
    for (int i = 0; i < 4; ++i) {
        int idx = threadIdx.x + i * 256;
        int kr = idx >> 4, c4 = idx & 15;
        f32x4 v = *(const f32x4*)&We[(size_t)(k0 + kr) * N + n0 + c4 * 4];
        #pragma unroll
        for (int j = 0; j < 4; ++j) t[c4 * 4 + j][kr] = f2bf(v[j]);
    }
    __syncthreads();
    #pragma unroll
    for (int i = 0; i < 2; ++i) {
        int idx = threadIdx.x + i * 256;
        int nr = idx >> 3, ck = idx & 7;
        u16x8 w;
        #pragma unroll
        for (int j = 0; j < 8; ++j) w[j] = t[nr][ck * 8 + j];
        *(u16x8*)&Wte[(size_t)(n0 + nr) * K + k0 + ck * 8] = w;
    }
}

// ---------------- router: logits + top-2 + compaction ----------------
__global__ __launch_bounds__(256) void router_kernel(
        const float* __restrict__ x, const float* __restrict__ rW,
        float* __restrict__ logits, int* __restrict__ selpk,
        int* __restrict__ slotpk, int* __restrict__ cnt, int* __restrict__ list) {
    __shared__ int se[8];
    __shared__ int sslot[8];
    int wid = threadIdx.x >> 6, lane = threadIdx.x & 63;
    int t = blockIdx.x * 4 + wid;
    const float* xr = x + (size_t)t * D_MODEL;
    float a0 = 0.f, a1 = 0.f, a2 = 0.f, a3 = 0.f;
    for (int d = lane; d < D_MODEL; d += 64) {
        float xv = xr[d];
        const float* w = rW + d * 4;
        a0 += xv * w[0]; a1 += xv * w[1]; a2 += xv * w[2]; a3 += xv * w[3];
    }
    #pragma unroll
    for (int off = 32; off; off >>= 1) {
        a0 += __shfl_xor(a0, off); a1 += __shfl_xor(a1, off);
        a2 += __shfl_xor(a2, off); a3 += __shfl_xor(a3, off);
    }
    if (lane == 0) {
        float l[4] = {a0, a1, a2, a3};
        logits[t * 4 + 0] = a0; logits[t * 4 + 1] = a1;
        logits[t * 4 + 2] = a2; logits[t * 4 + 3] = a3;
        int e0 = 0; float b = l[0];
        #pragma unroll
        for (int e = 1; e < 4; ++e) if (l[e] > b) { b = l[e]; e0 = e; }
        int e1 = -1; float b2 = -1e30f;
        #pragma unroll
        for (int e = 0; e < 4; ++e) {
            if (e == e0) continue;
            if (l[e] > b2) { b2 = l[e]; e1 = e; }
        }
        se[wid * 2] = e0; se[wid * 2 + 1] = e1;
    }
    __syncthreads();
    if (threadIdx.x == 0) {
        int cnts[4] = {0, 0, 0, 0}, base[4];
        #pragma unroll
        for (int k = 0; k < 8; ++k) cnts[se[k]]++;
        #pragma unroll
        for (int e = 0; e < 4; ++e)
            if (cnts[e]) base[e] = atomicAdd(&cnt[e * 32], cnts[e]);
        int run[4] = {0, 0, 0, 0};
        #pragma unroll
        for (int k = 0; k < 8; ++k) {
            int e = se[k];
            int s = base[e] + run[e]++;
            sslot[k] = s;
            list[e * NTOK + s] = blockIdx.x * 4 + (k >> 1);
        }
    }
    __syncthreads();
    if (lane == 0) {
        selpk[t] = se[wid * 2] | (se[wid * 2 + 1] << 8);
        slotpk[t] = sslot[wid * 2] | (sslot[wid * 2 + 1] << 16);
    }
}

// ---------------- pass1: h[slabrow] = gelu(gather(x) @ W1t[e]^T + b1) ----------------
__global__ __launch_bounds__(256) void pass1_kernel(
        const unsigned short* __restrict__ xb, const unsigned short* __restrict__ W1t,
        const float* __restrict__ b1, unsigned short* __restrict__ h,
        const int* __restrict__ cnt, const int* __restrict__ list, int fc, int BF) {
    __shared__ unsigned short As[128 * 64];
    __shared__ unsigned short Bs[128 * 64];
    const int e = blockIdx.z;
    const int tid = threadIdx.x, lane = tid & 63, wid = tid >> 6;
    int ecnt = NTOK, rowbase;
    if (e < 2) {
        rowbase = e * NTOK + blockIdx.y * 128;
    } else {
        int seg[4], pc[4];
        seg_of(cnt, seg, pc);
        int ev = e - 2;
        ecnt = cnt[ev * 32];
        if ((int)blockIdx.y * 128 >= pc[ev]) return;
        rowbase = seg[ev] + blockIdx.y * 128;
    }
    const int n0 = blockIdx.x * 128;

    // per-thread staging sources (row constant per j across K-steps)
    const unsigned short* asrc[4];
    const unsigned short* bsrc[4];
    const unsigned short* W1e = W1t + (size_t)e * D_FF * D_MODEL;
    #pragma unroll
    for (int j = 0; j < 4; ++j) {
        int row = (wid * 4 + j) * 8 + (lane >> 3);
        int kc = lane & 7;
        int tok;
        if (e < 2) tok = blockIdx.y * 128 + row;
        else {
            int s = blockIdx.y * 128 + row;
            tok = (s < ecnt) ? list[(e - 2) * NTOK + s] : 0;
        }
        asrc[j] = xb + (size_t)tok * D_MODEL + ((kc ^ (row & 7)) << 3);
        bsrc[j] = W1e + (size_t)(fc + n0 + row) * D_MODEL + ((kc ^ (row & 7)) << 3);
    }
    const int wm = (wid >> 1) * 64, wn = (wid & 1) * 64;

    f32x4 acc[4][4];
    #pragma unroll
    for (int i = 0; i < 4; ++i)
        #pragma unroll
        for (int j = 0; j < 4; ++j) acc[i][j] = (f32x4)0.f;

    for (int kb = 0; kb < D_MODEL; kb += 64) {
        #pragma unroll
        for (int j = 0; j < 4; ++j) gload16(asrc[j] + kb, &As[(wid * 4 + j) * 512]);
        #pragma unroll
        for (int j = 0; j < 4; ++j) gload16(bsrc[j] + kb, &Bs[(wid * 4 + j) * 512]);
        asm volatile("s_waitcnt vmcnt(0)" ::: "memory");
        __syncthreads();
        #pragma unroll
        for (int kk = 0; kk < 2; ++kk) {
            int kof = kk * 32 + (lane >> 4) * 8;
            bf16x8 a[4], b[4];
            #pragma unroll
            for (int mi = 0; mi < 4; ++mi) {
                int r = wm + mi * 16 + (lane & 15);
                a[mi] = *(const bf16x8*)&As[r * 64 + (kof ^ ((r & 7) << 3))];
            }
            #pragma unroll
            for (int ni = 0; ni < 4; ++ni) {
                int r = wn + ni * 16 + (lane & 15);
                b[ni] = *(const bf16x8*)&Bs[r * 64 + (kof ^ ((r & 7) << 3))];
            }
            #pragma unroll
            for (int mi = 0; mi < 4; ++mi)
                #pragma unroll
                for (int ni = 0; ni < 4; ++ni)
                    acc[mi][ni] = __builtin_amdgcn_mfma_f32_16x16x32_bf16(
                        a[mi], b[ni], acc[mi][ni], 0, 0, 0);
        }
        __syncthreads();
    }

    const float* b1e = b1 + (size_t)e * D_FF + fc + n0;
    #pragma unroll
    for (int ni = 0; ni < 4; ++ni) {
        int col = wn + ni * 16 + (lane & 15);
        float bias = b1e[col];
        #pragma unroll
        for (int mi = 0; mi < 4; ++mi) {
            #pragma unroll
            for (int j = 0; j < 4; ++j) {
                int row = wm + mi * 16 + (lane >> 4) * 4 + j;
                float v = acc[mi][ni][j] + bias;
                float g = 0.5f * v * (1.0f + erff(v * 0.70710678118654752f));
                h[(size_t)(rowbase + row) * BF + n0 + col] = f2bf(g);
            }
        }
    }
}

// ---------------- pass2: oslab[slabrow] (+)= h @ W2t[e]^T (+ b2) ----------------
__global__ __launch_bounds__(256) void pass2_kernel(
        const unsigned short* __restrict__ h, const unsigned short* __restrict__ W2t,
        const float* __restrict__ b2, float* __restrict__ oslab,
        const int* __restrict__ cnt, int fc, int BF, int first) {
    __shared__ unsigned short As[128 * 64];
    __shared__ unsigned short Bs[128 * 64];
    const int e = blockIdx.z;
    const int tid = threadIdx.x, lane = tid & 63, wid = tid >> 6;
    int rowbase;
    if (e < 2) {
        rowbase = e * NTOK + blockIdx.y * 128;
    } else {
        int seg[4], pc[4];
        seg_of(cnt, seg, pc);
        int ev = e - 2;
        if ((int)blockIdx.y * 128 >= pc[ev]) return;
        rowbase = seg[ev] + blockIdx.y * 128;
    }
    const int n0 = blockIdx.x * 128;

    const unsigned short* asrc[4];
    const unsigned short* bsrc[4];
    const unsigned short* W2e = W2t + (size_t)e * D_MODEL * D_FF;
    #pragma unroll
    for (int j = 0; j < 4; ++j) {
        int row = (wid * 4 + j) * 8 + (lane >> 3);
        int kc = lane & 7;
        asrc[j] = h + (size_t)(rowbase + row) * BF + ((kc ^ (row & 7)) << 3);
        bsrc[j] = W2e + (size_t)(n0 + row) * D_FF + fc + ((kc ^ (row & 7)) << 3);
    }
    const int wm = (wid >> 1) * 64, wn = (wid & 1) * 64;

    f32x4 acc[4][4];
    #pragma unroll
    for (int i = 0; i < 4; ++i)
        #pragma unroll
        for (int j = 0; j < 4; ++j) acc[i][j] = (f32x4)0.f;

    for (int kb = 0; kb < BF; kb += 64) {
        #pragma unroll
        for (int j = 0; j < 4; ++j) gload16(asrc[j] + kb, &As[(wid * 4 + j) * 512]);
        #pragma unroll
        for (int j = 0; j < 4; ++j) gload16(bsrc[j] + kb, &Bs[(wid * 4 + j) * 512]);
        asm volatile("s_waitcnt vmcnt(0)" ::: "memory");
        __syncthreads();
        #pragma unroll
        for (int kk = 0; kk < 2; ++kk) {
            int kof = kk * 32 + (lane >> 4) * 8;
            bf16x8 a[4], b[4];
            #pragma unroll
            for (int mi = 0; mi < 4; ++mi) {
                int r = wm + mi * 16 + (lane & 15);
                a[mi] = *(const bf16x8*)&As[r * 64 + (kof ^ ((r & 7) << 3))];
            }
            #pragma unroll
            for (int ni = 0; ni < 4; ++ni) {
                int r = wn + ni * 16 + (lane & 15);
                b[ni] = *(const bf16x8*)&Bs[r * 64 + (kof ^ ((r & 7) << 3))];
            }
            #pragma unroll
            for (int mi = 0; mi < 4; ++mi)
                #pragma unroll
                for (int ni = 0; ni < 4; ++ni)
                    acc[mi][ni] = __builtin_amdgcn_mfma_f32_16x16x32_bf16(
                        a[mi], b[ni], acc[mi][ni], 0, 0, 0);
        }
        __syncthreads();
    }

    const float* b2e = b2 + (size_t)e * D_MODEL + n0;
    #pragma unroll
    for (int ni = 0; ni < 4; ++ni) {
        int col = wn + ni * 16 + (lane & 15);
        float bias = first ? b2e[col] : 0.f;
        #pragma unroll
        for (int mi = 0; mi < 4; ++mi) {
            #pragma unroll
            for (int j = 0; j < 4; ++j) {
                int row = wm + mi * 16 + (lane >> 4) * 4 + j;
                size_t idx = (size_t)(rowbase + row) * D_MODEL + n0 + col;
                float v = acc[mi][ni][j] + bias;
                if (first) oslab[idx] = v;
                else       oslab[idx] += v;
            }
        }
    }
}

// ---------------- pass3: gather 4 rows, /4, LayerNorm ----------------
__global__ __launch_bounds__(256) void pass3_kernel(
        const float* __restrict__ oslab, const int* __restrict__ selpk,
        const int* __restrict__ slotpk, const int* __restrict__ cnt,
        const float* __restrict__ gamma, const float* __restrict__ beta,
        float* __restrict__ out) {
    int t = blockIdx.x;
    int seg[4], pc[4];
    seg_of(cnt, seg, pc);
    int sp = selpk[t], sl = slotpk[t];
    int e0 = sp & 0xff, e1 = (sp >> 8) & 0xff;
    int s0 = sl & 0xffff, s1 = (sl >> 16) & 0xffff;
    const float* p0 = oslab + (size_t)t * D_MODEL;
    const float* p1 = oslab + (size_t)(NTOK + t) * D_MODEL;
    const float* p2 = oslab + (size_t)(seg[e0] + s0) * D_MODEL;
    const float* p3 = oslab + (size_t)(seg[e1] + s1) * D_MODEL;
    float c[4];
    float sum = 0.f, sq = 0.f;
    #pragma unroll
    for (int i = 0; i < 4; ++i) {
        int d = threadIdx.x + i * 256;
        float v = (p0[d] + p1[d] + p2[d] + p3[d]) * 0.25f;
        c[i] = v; sum += v; sq += v * v;
    }
    #pragma unroll
    for (int off = 32; off; off >>= 1) {
        sum += __shfl_xor(sum, off);
        sq  += __shfl_xor(sq, off);
    }
    __shared__ float red[8];
    int lane = threadIdx.x & 63, wid = threadIdx.x >> 6;
    if (lane == 0) { red[wid] = sum; red[4 + wid] = sq; }
    __syncthreads();
    sum = red[0] + red[1] + red[2] + red[3];
    sq  = red[4] + red[5] + red[6] + red[7];
    float mean = sum * (1.0f / 1024.0f);
    float var = sq * (1.0f / 1024.0f) - mean * mean;
    float inv = rsqrtf(var + LN_EPS);
    #pragma unroll
    for (int i = 0; i < 4; ++i) {
        int d = threadIdx.x + i * 256;
        out[(size_t)t * D_MODEL + d] = (c[i] - mean) * inv * gamma[d] + beta[d];
    }
}

extern "C" void kernel_launch(void* const* d_in, const int* in_sizes, int n_in,
                              void* d_out, int out_size, void* d_ws, size_t ws_size,
                              hipStream_t stream) {
    const float* x   = (const float*)d_in[0];
    const float* rW  = (const float*)d_in[1];
    const float* W1  = (const float*)d_in[2];
    const float* b1  = (const float*)d_in[3];
    const float* W2  = (const float*)d_in[4];
    const float* b2  = (const float*)d_in[5];
    const float* gam = (const float*)d_in[6];
    const float* bet = (const float*)d_in[7];
    float* out = (float*)d_out;
    float* logits = out + (size_t)NTOK * D_MODEL;

    char* ws = (char*)d_ws;
    int* cnt    = (int*)ws;                     // 4 counters, 128B apart
    int* selpk  = (int*)(ws + 0x1000);
    int* slotpk = (int*)(ws + 0x6000);
    int* list   = (int*)(ws + 0xB000);          // 4*4096*4 = 64KB
    unsigned short* xb  = (unsigned short*)(ws + 0x20000);          // 8 MiB
    unsigned short* W1t = (unsigned short*)(ws + 0x820000);         // 48 MiB
    unsigned short* W2t = (unsigned short*)(ws + 0x3820000);        // 48 MiB
    float* oslab        = (float*)(ws + 0x6820000);                 // 16896*1024*4 = 66 MiB
    const size_t h_off  = 0x6820000 + (size_t)16896 * D_MODEL * 4;  // 0xAA20000
    unsigned short* h   = (unsigned short*)(ws + h_off);

    int BF = 1024;
    for (int cand = 4096; cand >= 1024; cand >>= 1) {
        size_t need = h_off + (size_t)16896 * cand * 2;
        if (need <= ws_size) { BF = cand; break; }
    }

    convx_kernel<<<NTOK * D_MODEL / 4 / 256, 256, 0, stream>>>(x, xb);
    transpose_kernel<<<dim3(D_FF / 64, D_MODEL / 64, 6), 256, 0, stream>>>(W1, W1t, D_MODEL, D_FF);
    transpose_kernel<<<dim3(D_MODEL / 64, D_FF / 64, 6), 256, 0, stream>>>(W2, W2t, D_FF, D_MODEL);
    hipMemsetAsync(cnt, 0, 512, stream);
    router_kernel<<<NTOK / 4, 256, 0, stream>>>(x, rW, logits, selpk, slotpk, cnt, list);

    int nch = D_FF / BF;
    for (int c = 0; c < nch; ++c) {
        pass1_kernel<<<dim3(BF / 128, 32, 6), 256, 0, stream>>>(
            xb, W1t, b1, h, cnt, list, c * BF, BF);
        pass2_kernel<<<dim3(D_MODEL / 128, 32, 6), 256, 0, stream>>>(
            h, W2t, b2, oslab, cnt, c * BF, BF, c == 0);
    }
    pass3_kernel<<<NTOK, 256, 0, stream>>>(oslab, selpk, slotpk, cnt, gam, bet, out);
}

// Round 3
// 548.378 us; speedup vs baseline: 1.7008x; 1.0890x over previous
//
#include <hip/hip_runtime.h>
#include <cstdint>
#include <cstddef>

#define D_MODEL 1024
#define D_FF 4096
#define NTOK 4096
#define LN_EPS 1e-5f

typedef __bf16 bf16x8 __attribute__((ext_vector_type(8)));
typedef float f32x4 __attribute__((ext_vector_type(4)));
typedef unsigned short u16x4 __attribute__((ext_vector_type(4)));
typedef unsigned short u16x8 __attribute__((ext_vector_type(8)));

static __device__ __forceinline__ unsigned short f2bf(float f) {
    union { float f; unsigned u; } v; v.f = f;
    unsigned r = v.u + 0x7fffu + ((v.u >> 16) & 1u);
    return (unsigned short)(r >> 16);
}

// tanh-form GELU as x*sigmoid(2u): ~8 VALU ops, error < 1e-3 (below bf16 rounding of h)
static __device__ __forceinline__ float gelu_fast(float x) {
    float x2 = x * x;
    float a = x * __builtin_fmaf(-0.0713548162726f, x2, -1.59576912161f); // -2u
    float e = __expf(a);
    return x * __builtin_amdgcn_rcpf(1.0f + e);
}

static __device__ __forceinline__ void gload16(const void* g, void* l) {
    __builtin_amdgcn_global_load_lds(
        (const __attribute__((address_space(1))) void*)g,
        (__attribute__((address_space(3))) void*)l, 16, 0, 0);
}

// padded prefix offsets of the 4 variable experts within the row slab
static __device__ __forceinline__ void seg_of(const int* cnt, int seg[4], int pc[4]) {
    int o = 2 * NTOK;
    #pragma unroll
    for (int e = 0; e < 4; ++e) {
        int c = cnt[e * 32];
        pc[e] = (c + 127) & ~127;
        seg[e] = o;
        o += pc[e];
    }
}

// ---------------- x: f32 -> bf16 ----------------
__global__ __launch_bounds__(256) void convx_kernel(const float* __restrict__ x,
                                                    unsigned short* __restrict__ xb) {
    int idx = blockIdx.x * 256 + threadIdx.x;   // float4 units
    f32x4 v = *(const f32x4*)&x[(size_t)idx * 4];
    u16x4 b;
    b[0] = f2bf(v[0]); b[1] = f2bf(v[1]); b[2] = f2bf(v[2]); b[3] = f2bf(v[3]);
    *(u16x4*)&xb[(size_t)idx * 4] = b;
}

// ---------------- W [E][K][N] f32 -> Wt [E][N][K] bf16 ----------------
__global__ __launch_bounds__(256) void transpose_kernel(const float* __restrict__ W,
                                                        unsigned short* __restrict__ Wt,
                                                        int K, int N) {
    __shared__ unsigned short t[64][65];
    int k0 = blockIdx.y * 64, n0 = blockIdx.x * 64;
    const float* We = W + (size_t)blockIdx.z * K * N;
    unsigned short* Wte = Wt + (size_t)blockIdx.z * K * N;
    #pragma unroll
    for (int i = 0; i < 4; ++i) {
        int idx = threadIdx.x + i * 256;
        int kr = idx >> 4, c4 = idx & 15;
        f32x4 v = *(const f32x4*)&We[(size_t)(k0 + kr) * N + n0 + c4 * 4];
        #pragma unroll
        for (int j = 0; j < 4; ++j) t[c4 * 4 + j][kr] = f2bf(v[j]);
    }
    __syncthreads();
    #pragma unroll
    for (int i = 0; i < 2; ++i) {
        int idx = threadIdx.x + i * 256;
        int nr = idx >> 3, ck = idx & 7;
        u16x8 w;
        #pragma unroll
        for (int j = 0; j < 8; ++j) w[j] = t[nr][ck * 8 + j];
        *(u16x8*)&Wte[(size_t)(n0 + nr) * K + k0 + ck * 8] = w;
    }
}

// ---------------- router: logits + top-2 + compaction ----------------
__global__ __launch_bounds__(256) void router_kernel(
        const float* __restrict__ x, const float* __restrict__ rW,
        float* __restrict__ logits, int* __restrict__ selpk,
        int* __restrict__ slotpk, int* __restrict__ cnt, int* __restrict__ list) {
    __shared__ int se[8];
    __shared__ int sslot[8];
    int wid = threadIdx.x >> 6, lane = threadIdx.x & 63;
    int t = blockIdx.x * 4 + wid;
    const float* xr = x + (size_t)t * D_MODEL;
    float a0 = 0.f, a1 = 0.f, a2 = 0.f, a3 = 0.f;
    for (int d = lane; d < D_MODEL; d += 64) {
        float xv = xr[d];
        const float* w = rW + d * 4;
        a0 += xv * w[0]; a1 += xv * w[1]; a2 += xv * w[2]; a3 += xv * w[3];
    }
    #pragma unroll
    for (int off = 32; off; off >>= 1) {
        a0 += __shfl_xor(a0, off); a1 += __shfl_xor(a1, off);
        a2 += __shfl_xor(a2, off); a3 += __shfl_xor(a3, off);
    }
    if (lane == 0) {
        float l[4] = {a0, a1, a2, a3};
        logits[t * 4 + 0] = a0; logits[t * 4 + 1] = a1;
        logits[t * 4 + 2] = a2; logits[t * 4 + 3] = a3;
        int e0 = 0; float b = l[0];
        #pragma unroll
        for (int e = 1; e < 4; ++e) if (l[e] > b) { b = l[e]; e0 = e; }
        int e1 = -1; float b2 = -1e30f;
        #pragma unroll
        for (int e = 0; e < 4; ++e) {
            if (e == e0) continue;
            if (l[e] > b2) { b2 = l[e]; e1 = e; }
        }
        se[wid * 2] = e0; se[wid * 2 + 1] = e1;
    }
    __syncthreads();
    if (threadIdx.x == 0) {
        int cnts[4] = {0, 0, 0, 0}, base[4];
        #pragma unroll
        for (int k = 0; k < 8; ++k) cnts[se[k]]++;
        #pragma unroll
        for (int e = 0; e < 4; ++e)
            if (cnts[e]) base[e] = atomicAdd(&cnt[e * 32], cnts[e]);
        int run[4] = {0, 0, 0, 0};
        #pragma unroll
        for (int k = 0; k < 8; ++k) {
            int e = se[k];
            int s = base[e] + run[e]++;
            sslot[k] = s;
            list[e * NTOK + s] = blockIdx.x * 4 + (k >> 1);
        }
    }
    __syncthreads();
    if (lane == 0) {
        selpk[t] = se[wid * 2] | (se[wid * 2 + 1] << 8);
        slotpk[t] = sslot[wid * 2] | (sslot[wid * 2 + 1] << 16);
    }
}

// ---------------- pass1: h[slabrow] = gelu(gather(x) @ W1t[e]^T + b1) ----------------
__global__ __launch_bounds__(256) void pass1_kernel(
        const unsigned short* __restrict__ xb, const unsigned short* __restrict__ W1t,
        const float* __restrict__ b1, unsigned short* __restrict__ h,
        const int* __restrict__ cnt, const int* __restrict__ list, int fc, int BF) {
    __shared__ unsigned short As[128 * 64];
    __shared__ unsigned short Bs[128 * 64];
    const int e = blockIdx.z;
    const int tid = threadIdx.x, lane = tid & 63, wid = tid >> 6;
    int ecnt = NTOK, rowbase;
    if (e < 2) {
        rowbase = e * NTOK + blockIdx.y * 128;
    } else {
        int seg[4], pc[4];
        seg_of(cnt, seg, pc);
        int ev = e - 2;
        ecnt = cnt[ev * 32];
        if ((int)blockIdx.y * 128 >= pc[ev]) return;
        rowbase = seg[ev] + blockIdx.y * 128;
    }
    const int n0 = blockIdx.x * 128;

    // per-thread staging sources (row constant per j across K-steps)
    const unsigned short* asrc[4];
    const unsigned short* bsrc[4];
    const unsigned short* W1e = W1t + (size_t)e * D_FF * D_MODEL;
    #pragma unroll
    for (int j = 0; j < 4; ++j) {
        int row = (wid * 4 + j) * 8 + (lane >> 3);
        int kc = lane & 7;
        int tok;
        if (e < 2) tok = blockIdx.y * 128 + row;
        else {
            int s = blockIdx.y * 128 + row;
            tok = (s < ecnt) ? list[(e - 2) * NTOK + s] : 0;
        }
        asrc[j] = xb + (size_t)tok * D_MODEL + ((kc ^ (row & 7)) << 3);
        bsrc[j] = W1e + (size_t)(fc + n0 + row) * D_MODEL + ((kc ^ (row & 7)) << 3);
    }
    const int wm = (wid >> 1) * 64, wn = (wid & 1) * 64;

    f32x4 acc[4][4];
    #pragma unroll
    for (int i = 0; i < 4; ++i)
        #pragma unroll
        for (int j = 0; j < 4; ++j) acc[i][j] = (f32x4)0.f;

    for (int kb = 0; kb < D_MODEL; kb += 64) {
        #pragma unroll
        for (int j = 0; j < 4; ++j) gload16(asrc[j] + kb, &As[(wid * 4 + j) * 512]);
        #pragma unroll
        for (int j = 0; j < 4; ++j) gload16(bsrc[j] + kb, &Bs[(wid * 4 + j) * 512]);
        asm volatile("s_waitcnt vmcnt(0)" ::: "memory");
        __syncthreads();
        #pragma unroll
        for (int kk = 0; kk < 2; ++kk) {
            int kof = kk * 32 + (lane >> 4) * 8;
            bf16x8 a[4], b[4];
            #pragma unroll
            for (int mi = 0; mi < 4; ++mi) {
                int r = wm + mi * 16 + (lane & 15);
                a[mi] = *(const bf16x8*)&As[r * 64 + (kof ^ ((r & 7) << 3))];
            }
            #pragma unroll
            for (int ni = 0; ni < 4; ++ni) {
                int r = wn + ni * 16 + (lane & 15);
                b[ni] = *(const bf16x8*)&Bs[r * 64 + (kof ^ ((r & 7) << 3))];
            }
            #pragma unroll
            for (int mi = 0; mi < 4; ++mi)
                #pragma unroll
                for (int ni = 0; ni < 4; ++ni)
                    acc[mi][ni] = __builtin_amdgcn_mfma_f32_16x16x32_bf16(
                        a[mi], b[ni], acc[mi][ni], 0, 0, 0);
        }
        __syncthreads();
    }

    const float* b1e = b1 + (size_t)e * D_FF + fc + n0;
    #pragma unroll
    for (int ni = 0; ni < 4; ++ni) {
        int col = wn + ni * 16 + (lane & 15);
        float bias = b1e[col];
        #pragma unroll
        for (int mi = 0; mi < 4; ++mi) {
            #pragma unroll
            for (int j = 0; j < 4; ++j) {
                int row = wm + mi * 16 + (lane >> 4) * 4 + j;
                float v = acc[mi][ni][j] + bias;
                h[(size_t)(rowbase + row) * BF + n0 + col] = f2bf(gelu_fast(v));
            }
        }
    }
}

// ---------------- pass2: oslab[slabrow] (+)= h @ W2t[e]^T (+ b2) ----------------
__global__ __launch_bounds__(256) void pass2_kernel(
        const unsigned short* __restrict__ h, const unsigned short* __restrict__ W2t,
        const float* __restrict__ b2, float* __restrict__ oslab,
        const int* __restrict__ cnt, int fc, int BF, int first) {
    __shared__ unsigned short As[128 * 64];
    __shared__ unsigned short Bs[128 * 64];
    const int e = blockIdx.z;
    const int tid = threadIdx.x, lane = tid & 63, wid = tid >> 6;
    int rowbase;
    if (e < 2) {
        rowbase = e * NTOK + blockIdx.y * 128;
    } else {
        int seg[4], pc[4];
        seg_of(cnt, seg, pc);
        int ev = e - 2;
        if ((int)blockIdx.y * 128 >= pc[ev]) return;
        rowbase = seg[ev] + blockIdx.y * 128;
    }
    const int n0 = blockIdx.x * 128;

    const unsigned short* asrc[4];
    const unsigned short* bsrc[4];
    const unsigned short* W2e = W2t + (size_t)e * D_MODEL * D_FF;
    #pragma unroll
    for (int j = 0; j < 4; ++j) {
        int row = (wid * 4 + j) * 8 + (lane >> 3);
        int kc = lane & 7;
        asrc[j] = h + (size_t)(rowbase + row) * BF + ((kc ^ (row & 7)) << 3);
        bsrc[j] = W2e + (size_t)(n0 + row) * D_FF + fc + ((kc ^ (row & 7)) << 3);
    }
    const int wm = (wid >> 1) * 64, wn = (wid & 1) * 64;

    f32x4 acc[4][4];
    #pragma unroll
    for (int i = 0; i < 4; ++i)
        #pragma unroll
        for (int j = 0; j < 4; ++j) acc[i][j] = (f32x4)0.f;

    for (int kb = 0; kb < BF; kb += 64) {
        #pragma unroll
        for (int j = 0; j < 4; ++j) gload16(asrc[j] + kb, &As[(wid * 4 + j) * 512]);
        #pragma unroll
        for (int j = 0; j < 4; ++j) gload16(bsrc[j] + kb, &Bs[(wid * 4 + j) * 512]);
        asm volatile("s_waitcnt vmcnt(0)" ::: "memory");
        __syncthreads();
        #pragma unroll
        for (int kk = 0; kk < 2; ++kk) {
            int kof = kk * 32 + (lane >> 4) * 8;
            bf16x8 a[4], b[4];
            #pragma unroll
            for (int mi = 0; mi < 4; ++mi) {
                int r = wm + mi * 16 + (lane & 15);
                a[mi] = *(const bf16x8*)&As[r * 64 + (kof ^ ((r & 7) << 3))];
            }
            #pragma unroll
            for (int ni = 0; ni < 4; ++ni) {
                int r = wn + ni * 16 + (lane & 15);
                b[ni] = *(const bf16x8*)&Bs[r * 64 + (kof ^ ((r & 7) << 3))];
            }
            #pragma unroll
            for (int mi = 0; mi < 4; ++mi)
                #pragma unroll
                for (int ni = 0; ni < 4; ++ni)
                    acc[mi][ni] = __builtin_amdgcn_mfma_f32_16x16x32_bf16(
                        a[mi], b[ni], acc[mi][ni], 0, 0, 0);
        }
        __syncthreads();
    }

    const float* b2e = b2 + (size_t)e * D_MODEL + n0;
    #pragma unroll
    for (int ni = 0; ni < 4; ++ni) {
        int col = wn + ni * 16 + (lane & 15);
        float bias = first ? b2e[col] : 0.f;
        #pragma unroll
        for (int mi = 0; mi < 4; ++mi) {
            #pragma unroll
            for (int j = 0; j < 4; ++j) {
                int row = wm + mi * 16 + (lane >> 4) * 4 + j;
                size_t idx = (size_t)(rowbase + row) * D_MODEL + n0 + col;
                float v = acc[mi][ni][j] + bias;
                if (first) oslab[idx] = v;
                else       oslab[idx] += v;
            }
        }
    }
}

// ---------------- pass3: gather 4 rows, /4, LayerNorm ----------------
__global__ __launch_bounds__(256) void pass3_kernel(
        const float* __restrict__ oslab, const int* __restrict__ selpk,
        const int* __restrict__ slotpk, const int* __restrict__ cnt,
        const float* __restrict__ gamma, const float* __restrict__ beta,
        float* __restrict__ out) {
    int t = blockIdx.x;
    int seg[4], pc[4];
    seg_of(cnt, seg, pc);
    int sp = selpk[t], sl = slotpk[t];
    int e0 = sp & 0xff, e1 = (sp >> 8) & 0xff;
    int s0 = sl & 0xffff, s1 = (sl >> 16) & 0xffff;
    const float* p0 = oslab + (size_t)t * D_MODEL;
    const float* p1 = oslab + (size_t)(NTOK + t) * D_MODEL;
    const float* p2 = oslab + (size_t)(seg[e0] + s0) * D_MODEL;
    const float* p3 = oslab + (size_t)(seg[e1] + s1) * D_MODEL;
    float c[4];
    float sum = 0.f, sq = 0.f;
    #pragma unroll
    for (int i = 0; i < 4; ++i) {
        int d = threadIdx.x + i * 256;
        float v = (p0[d] + p1[d] + p2[d] + p3[d]) * 0.25f;
        c[i] = v; sum += v; sq += v * v;
    }
    #pragma unroll
    for (int off = 32; off; off >>= 1) {
        sum += __shfl_xor(sum, off);
        sq  += __shfl_xor(sq, off);
    }
    __shared__ float red[8];
    int lane = threadIdx.x & 63, wid = threadIdx.x >> 6;
    if (lane == 0) { red[wid] = sum; red[4 + wid] = sq; }
    __syncthreads();
    sum = red[0] + red[1] + red[2] + red[3];
    sq  = red[4] + red[5] + red[6] + red[7];
    float mean = sum * (1.0f / 1024.0f);
    float var = sq * (1.0f / 1024.0f) - mean * mean;
    float inv = rsqrtf(var + LN_EPS);
    #pragma unroll
    for (int i = 0; i < 4; ++i) {
        int d = threadIdx.x + i * 256;
        out[(size_t)t * D_MODEL + d] = (c[i] - mean) * inv * gamma[d] + beta[d];
    }
}

extern "C" void kernel_launch(void* const* d_in, const int* in_sizes, int n_in,
                              void* d_out, int out_size, void* d_ws, size_t ws_size,
                              hipStream_t stream) {
    const float* x   = (const float*)d_in[0];
    const float* rW  = (const float*)d_in[1];
    const float* W1  = (const float*)d_in[2];
    const float* b1  = (const float*)d_in[3];
    const float* W2  = (const float*)d_in[4];
    const float* b2  = (const float*)d_in[5];
    const float* gam = (const float*)d_in[6];
    const float* bet = (const float*)d_in[7];
    float* out = (float*)d_out;
    float* logits = out + (size_t)NTOK * D_MODEL;

    char* ws = (char*)d_ws;
    int* cnt    = (int*)ws;                     // 4 counters, 128B apart
    int* selpk  = (int*)(ws + 0x1000);
    int* slotpk = (int*)(ws + 0x6000);
    int* list   = (int*)(ws + 0xB000);          // 4*4096*4 = 64KB
    unsigned short* xb  = (unsigned short*)(ws + 0x20000);          // 8 MiB
    unsigned short* W1t = (unsigned short*)(ws + 0x820000);         // 48 MiB
    unsigned short* W2t = (unsigned short*)(ws + 0x3820000);        // 48 MiB
    float* oslab        = (float*)(ws + 0x6820000);                 // 16896*1024*4 = 66 MiB
    const size_t h_off  = 0x6820000 + (size_t)16896 * D_MODEL * 4;  // 0xAA20000
    unsigned short* h   = (unsigned short*)(ws + h_off);

    int BF = 1024;
    for (int cand = 4096; cand >= 1024; cand >>= 1) {
        size_t need = h_off + (size_t)16896 * cand * 2;
        if (need <= ws_size) { BF = cand; break; }
    }

    convx_kernel<<<NTOK * D_MODEL / 4 / 256, 256, 0, stream>>>(x, xb);
    transpose_kernel<<<dim3(D_FF / 64, D_MODEL / 64, 6), 256, 0, stream>>>(W1, W1t, D_MODEL, D_FF);
    transpose_kernel<<<dim3(D_MODEL / 64, D_FF / 64, 6), 256, 0, stream>>>(W2, W2t, D_FF, D_MODEL);
    hipMemsetAsync(cnt, 0, 512, stream);
    router_kernel<<<NTOK / 4, 256, 0, stream>>>(x, rW, logits, selpk, slotpk, cnt, list);

    int nch = D_FF / BF;
    for (int c = 0; c < nch; ++c) {
        pass1_kernel<<<dim3(BF / 128, 32, 6), 256, 0, stream>>>(
            xb, W1t, b1, h, cnt, list, c * BF, BF);
        pass2_kernel<<<dim3(D_MODEL / 128, 32, 6), 256, 0, stream>>>(
            h, W2t, b2, oslab, cnt, c * BF, BF, c == 0);
    }
    pass3_kernel<<<NTOK, 256, 0, stream>>>(oslab, selpk, slotpk, cnt, gam, bet, out);
}

// Round 4
// 548.186 us; speedup vs baseline: 1.7014x; 1.0004x over previous
//
#include <hip/hip_runtime.h>
#include <cstdint>
#include <cstddef>

#define D_MODEL 1024
#define D_FF 4096
#define NTOK 4096
#define LN_EPS 1e-5f
#define SLAB_ROWS 17408   // 2*4096 fixed + (8192 + 4*256) padded variable bound

typedef __bf16 bf16x8 __attribute__((ext_vector_type(8)));
typedef float f32x4 __attribute__((ext_vector_type(4)));
typedef unsigned short u16x4 __attribute__((ext_vector_type(4)));
typedef unsigned short u16x8 __attribute__((ext_vector_type(8)));

static __device__ __forceinline__ unsigned short f2bf(float f) {
    union { float f; unsigned u; } v; v.f = f;
    unsigned r = v.u + 0x7fffu + ((v.u >> 16) & 1u);
    return (unsigned short)(r >> 16);
}

static __device__ __forceinline__ float b2f(unsigned short u) {
    union { unsigned u; float f; } v; v.u = (unsigned)u << 16;
    return v.f;
}

// tanh-form GELU as x*sigmoid(2u): ~8 VALU ops (proven round 3)
static __device__ __forceinline__ float gelu_fast(float x) {
    float x2 = x * x;
    float a = x * __builtin_fmaf(-0.0713548162726f, x2, -1.59576912161f); // -2u
    float e = __expf(a);
    return x * __builtin_amdgcn_rcpf(1.0f + e);
}

static __device__ __forceinline__ void gload16(const void* g, void* l) {
    __builtin_amdgcn_global_load_lds(
        (const __attribute__((address_space(1))) void*)g,
        (__attribute__((address_space(3))) void*)l, 16, 0, 0);
}

// padded (256-aligned) prefix offsets of the 4 variable experts in the row slab
static __device__ __forceinline__ void seg_of(const int* cnt, int seg[4], int pc[4]) {
    int o = 2 * NTOK;
    #pragma unroll
    for (int e = 0; e < 4; ++e) {
        int c = cnt[e * 32];
        pc[e] = (c + 255) & ~255;
        seg[e] = o;
        o += pc[e];
    }
}

// ---------------- x: f32 -> bf16 ----------------
__global__ __launch_bounds__(256) void convx_kernel(const float* __restrict__ x,
                                                    unsigned short* __restrict__ xb) {
    int idx = blockIdx.x * 256 + threadIdx.x;   // float4 units
    f32x4 v = *(const f32x4*)&x[(size_t)idx * 4];
    u16x4 b;
    b[0] = f2bf(v[0]); b[1] = f2bf(v[1]); b[2] = f2bf(v[2]); b[3] = f2bf(v[3]);
    *(u16x4*)&xb[(size_t)idx * 4] = b;
}

// ---------------- W [E][K][N] f32 -> Wt [E][N][K] bf16 ----------------
__global__ __launch_bounds__(256) void transpose_kernel(const float* __restrict__ W,
                                                        unsigned short* __restrict__ Wt,
                                                        int K, int N) {
    __shared__ unsigned short t[64][65];
    int k0 = blockIdx.y * 64, n0 = blockIdx.x * 64;
    const float* We = W + (size_t)blockIdx.z * K * N;
    unsigned short* Wte = Wt + (size_t)blockIdx.z * K * N;
    #pragma unroll
    for (int i = 0; i < 4; ++i) {
        int idx = threadIdx.x + i * 256;
        int kr = idx >> 4, c4 = idx & 15;
        f32x4 v = *(const f32x4*)&We[(size_t)(k0 + kr) * N + n0 + c4 * 4];
        #pragma unroll
        for (int j = 0; j < 4; ++j) t[c4 * 4 + j][kr] = f2bf(v[j]);
    }
    __syncthreads();
    #pragma unroll
    for (int i = 0; i < 2; ++i) {
        int idx = threadIdx.x + i * 256;
        int nr = idx >> 3, ck = idx & 7;
        u16x8 w;
        #pragma unroll
        for (int j = 0; j < 8; ++j) w[j] = t[nr][ck * 8 + j];
        *(u16x8*)&Wte[(size_t)(n0 + nr) * K + k0 + ck * 8] = w;
    }
}

// ---------------- router: logits + top-2 + compaction ----------------
__global__ __launch_bounds__(256) void router_kernel(
        const float* __restrict__ x, const float* __restrict__ rW,
        float* __restrict__ logits, int* __restrict__ selpk,
        int* __restrict__ slotpk, int* __restrict__ cnt, int* __restrict__ list) {
    __shared__ int se[8];
    __shared__ int sslot[8];
    int wid = threadIdx.x >> 6, lane = threadIdx.x & 63;
    int t = blockIdx.x * 4 + wid;
    const float* xr = x + (size_t)t * D_MODEL;
    float a0 = 0.f, a1 = 0.f, a2 = 0.f, a3 = 0.f;
    for (int d = lane; d < D_MODEL; d += 64) {
        float xv = xr[d];
        const float* w = rW + d * 4;
        a0 += xv * w[0]; a1 += xv * w[1]; a2 += xv * w[2]; a3 += xv * w[3];
    }
    #pragma unroll
    for (int off = 32; off; off >>= 1) {
        a0 += __shfl_xor(a0, off); a1 += __shfl_xor(a1, off);
        a2 += __shfl_xor(a2, off); a3 += __shfl_xor(a3, off);
    }
    if (lane == 0) {
        float l[4] = {a0, a1, a2, a3};
        logits[t * 4 + 0] = a0; logits[t * 4 + 1] = a1;
        logits[t * 4 + 2] = a2; logits[t * 4 + 3] = a3;
        int e0 = 0; float b = l[0];
        #pragma unroll
        for (int e = 1; e < 4; ++e) if (l[e] > b) { b = l[e]; e0 = e; }
        int e1 = -1; float b2 = -1e30f;
        #pragma unroll
        for (int e = 0; e < 4; ++e) {
            if (e == e0) continue;
            if (l[e] > b2) { b2 = l[e]; e1 = e; }
        }
        se[wid * 2] = e0; se[wid * 2 + 1] = e1;
    }
    __syncthreads();
    if (threadIdx.x == 0) {
        int cnts[4] = {0, 0, 0, 0}, base[4];
        #pragma unroll
        for (int k = 0; k < 8; ++k) cnts[se[k]]++;
        #pragma unroll
        for (int e = 0; e < 4; ++e)
            if (cnts[e]) base[e] = atomicAdd(&cnt[e * 32], cnts[e]);
        int run[4] = {0, 0, 0, 0};
        #pragma unroll
        for (int k = 0; k < 8; ++k) {
            int e = se[k];
            int s = base[e] + run[e]++;
            sslot[k] = s;
            list[e * NTOK + s] = blockIdx.x * 4 + (k >> 1);
        }
    }
    __syncthreads();
    if (lane == 0) {
        selpk[t] = se[wid * 2] | (se[wid * 2 + 1] << 8);
        slotpk[t] = sslot[wid * 2] | (sslot[wid * 2 + 1] << 16);
    }
}

// ---------------- unified 256x256 8-phase GEMM ----------------
// GELU=1: pass1  out = gelu(gather(x) @ W1t^T + b1), bf16
// GELU=0: pass2  out = h @ W2t^T + b2, bf16
// A rows are K-contiguous (ld == K); B rows are K-contiguous (ld == K).
// 8 waves (2M x 4N), per-wave C = 128x64. Double-buffered 128KiB LDS.
// Counted vmcnt(8) pipeline: stage t+2 after last read of tile t; never drain
// vmcnt to 0 in steady state (T3+T4); setprio around MFMA clusters (T5).
template<int GELU>
__global__ __launch_bounds__(512, 2) void gemm8_kernel(
        const unsigned short* __restrict__ A, const unsigned short* __restrict__ B,
        const float* __restrict__ bias, int bias_stride, int ldo,
        unsigned short* __restrict__ out,
        const int* __restrict__ cnt, const int* __restrict__ list, int K) {
    __shared__ unsigned short lds[2][2][256 * 64];
    const int e = blockIdx.z;
    const int tid = threadIdx.x, l = tid & 63, w = tid >> 6;
    int rowbase;
    int ecnt = NTOK;
    if (e < 2) {
        rowbase = e * NTOK + blockIdx.y * 256;
    } else {
        int seg[4], pc[4];
        seg_of(cnt, seg, pc);
        int ev = e - 2;
        ecnt = cnt[ev * 32];
        if ((int)blockIdx.y * 256 >= pc[ev]) return;   // before any barrier
        rowbase = seg[ev] + blockIdx.y * 256;
    }
    const int n0 = blockIdx.x * 256;
    const unsigned short* Be = B + (size_t)e * (4096 * 1024);

    // staging sources: load i covers rows i*64 + w*8 + (l>>3); 16B piece l&7,
    // source pre-swizzled by ((l&7) ^ (row&7)) so linear LDS dest + swizzled
    // read form the same involution (rule 21).
    const unsigned short* asrc[4];
    const unsigned short* bsrc[4];
    #pragma unroll
    for (int i = 0; i < 4; ++i) {
        int row = i * 64 + w * 8 + (l >> 3);
        int piece = ((l & 7) ^ (row & 7)) << 3;
        size_t arow;
        if (GELU) {
            int s = blockIdx.y * 256 + row;
            if (e < 2) arow = (size_t)s;
            else       arow = (size_t)((s < ecnt) ? list[(e - 2) * NTOK + s] : 0);
        } else {
            arow = (size_t)(rowbase + row);
        }
        asrc[i] = A + arow * K + piece;
        bsrc[i] = Be + (size_t)(n0 + row) * K + piece;
    }

    const int wr = w >> 2, wc = w & 3;
    const int rl = l & 15, kq = l >> 4;

    // preload bias BEFORE any staging so no stray VMEM perturbs vmcnt counting
    float bv[4];
    #pragma unroll
    for (int ni = 0; ni < 4; ++ni)
        bv[ni] = bias[(size_t)e * bias_stride + n0 + wc * 64 + ni * 16 + rl];

    f32x4 acc[8][4];
    #pragma unroll
    for (int i = 0; i < 8; ++i)
        #pragma unroll
        for (int j = 0; j < 4; ++j) acc[i][j] = (f32x4)0.f;

    const int nt = K / 64;

    // stage one K-tile (A+B, 256x64 each) into buffer b: 8 gloads/thread
    #define STAGE(bf, t)                                                        \
        {                                                                       \
            unsigned short* la = &lds[bf][0][(w * 8) * 64];                     \
            unsigned short* lb = &lds[bf][1][(w * 8) * 64];                     \
            _Pragma("unroll")                                                   \
            for (int i = 0; i < 4; ++i) {                                       \
                gload16(asrc[i] + (t) * 64, la + i * 4096);                     \
                gload16(bsrc[i] + (t) * 64, lb + i * 4096);                     \
            }                                                                   \
        }

    STAGE(0, 0);
    STAGE(1, 1);

    for (int t = 0; t < nt; ++t) {
        const int cur = t & 1;
        if (t < nt - 1) { asm volatile("s_waitcnt vmcnt(8)" ::: "memory"); }
        else            { asm volatile("s_waitcnt vmcnt(0)" ::: "memory"); }
        __builtin_amdgcn_s_barrier();              // tile t visible to all waves
        const unsigned short* LA = &lds[cur][0][0];
        const unsigned short* LB = &lds[cur][1][0];
        #pragma unroll
        for (int kk = 0; kk < 2; ++kk) {
            bf16x8 bfr[4];
            #pragma unroll
            for (int ni = 0; ni < 4; ++ni) {
                int n = wc * 64 + ni * 16 + rl;
                bfr[ni] = *(const bf16x8*)&LB[n * 64 + (((kk * 4 + kq) ^ (n & 7)) << 3)];
            }
            #pragma unroll
            for (int mh = 0; mh < 2; ++mh) {
                bf16x8 afr[4];
                #pragma unroll
                for (int i = 0; i < 4; ++i) {
                    int r = wr * 128 + (mh * 4 + i) * 16 + rl;
                    afr[i] = *(const bf16x8*)&LA[r * 64 + (((kk * 4 + kq) ^ (r & 7)) << 3)];
                }
                __builtin_amdgcn_s_barrier();      // phase align
                __builtin_amdgcn_s_setprio(1);
                #pragma unroll
                for (int i = 0; i < 4; ++i)
                    #pragma unroll
                    for (int ni = 0; ni < 4; ++ni)
                        acc[mh * 4 + i][ni] = __builtin_amdgcn_mfma_f32_16x16x32_bf16(
                            afr[i], bfr[ni], acc[mh * 4 + i][ni], 0, 0, 0);
                __builtin_amdgcn_s_setprio(0);
                __builtin_amdgcn_s_barrier();      // phase end
            }
        }
        // all waves past their last read of buf[cur] (final phase barrier)
        if (t + 2 < nt) STAGE(cur, t + 2);
    }
    #undef STAGE

    // epilogue
    #pragma unroll
    for (int ni = 0; ni < 4; ++ni) {
        int c = n0 + wc * 64 + ni * 16 + rl;
        #pragma unroll
        for (int mi = 0; mi < 8; ++mi) {
            #pragma unroll
            for (int j = 0; j < 4; ++j) {
                int r = wr * 128 + mi * 16 + kq * 4 + j;
                float v = acc[mi][ni][j] + bv[ni];
                if (GELU) v = gelu_fast(v);
                out[(size_t)(rowbase + r) * ldo + c] = f2bf(v);
            }
        }
    }
}

// ---------------- pass3: gather 4 bf16 rows, /4, LayerNorm ----------------
__global__ __launch_bounds__(256) void pass3_kernel(
        const unsigned short* __restrict__ oslab, const int* __restrict__ selpk,
        const int* __restrict__ slotpk, const int* __restrict__ cnt,
        const float* __restrict__ gamma, const float* __restrict__ beta,
        float* __restrict__ out) {
    int t = blockIdx.x;
    int seg[4], pc[4];
    seg_of(cnt, seg, pc);
    int sp = selpk[t], sl = slotpk[t];
    int e0 = sp & 0xff, e1 = (sp >> 8) & 0xff;
    int s0 = sl & 0xffff, s1 = (sl >> 16) & 0xffff;
    const unsigned short* p0 = oslab + (size_t)t * D_MODEL;
    const unsigned short* p1 = oslab + (size_t)(NTOK + t) * D_MODEL;
    const unsigned short* p2 = oslab + (size_t)(seg[e0] + s0) * D_MODEL;
    const unsigned short* p3 = oslab + (size_t)(seg[e1] + s1) * D_MODEL;
    float c[4];
    float sum = 0.f, sq = 0.f;
    #pragma unroll
    for (int i = 0; i < 4; ++i) {
        int d = threadIdx.x + i * 256;
        float v = (b2f(p0[d]) + b2f(p1[d]) + b2f(p2[d]) + b2f(p3[d])) * 0.25f;
        c[i] = v; sum += v; sq += v * v;
    }
    #pragma unroll
    for (int off = 32; off; off >>= 1) {
        sum += __shfl_xor(sum, off);
        sq  += __shfl_xor(sq, off);
    }
    __shared__ float red[8];
    int lane = threadIdx.x & 63, wid = threadIdx.x >> 6;
    if (lane == 0) { red[wid] = sum; red[4 + wid] = sq; }
    __syncthreads();
    sum = red[0] + red[1] + red[2] + red[3];
    sq  = red[4] + red[5] + red[6] + red[7];
    float mean = sum * (1.0f / 1024.0f);
    float var = sq * (1.0f / 1024.0f) - mean * mean;
    float inv = rsqrtf(var + LN_EPS);
    #pragma unroll
    for (int i = 0; i < 4; ++i) {
        int d = threadIdx.x + i * 256;
        out[(size_t)t * D_MODEL + d] = (c[i] - mean) * inv * gamma[d] + beta[d];
    }
}

extern "C" void kernel_launch(void* const* d_in, const int* in_sizes, int n_in,
                              void* d_out, int out_size, void* d_ws, size_t ws_size,
                              hipStream_t stream) {
    const float* x   = (const float*)d_in[0];
    const float* rW  = (const float*)d_in[1];
    const float* W1  = (const float*)d_in[2];
    const float* b1  = (const float*)d_in[3];
    const float* W2  = (const float*)d_in[4];
    const float* b2  = (const float*)d_in[5];
    const float* gam = (const float*)d_in[6];
    const float* bet = (const float*)d_in[7];
    float* out = (float*)d_out;
    float* logits = out + (size_t)NTOK * D_MODEL;

    char* ws = (char*)d_ws;
    int* cnt    = (int*)ws;                     // 4 counters, 128B apart
    int* selpk  = (int*)(ws + 0x1000);
    int* slotpk = (int*)(ws + 0x6000);
    int* list   = (int*)(ws + 0xB000);          // 4*4096*4 = 64KB
    unsigned short* xb    = (unsigned short*)(ws + 0x20000);    // 8 MiB
    unsigned short* W1t   = (unsigned short*)(ws + 0x820000);   // 48 MiB
    unsigned short* W2t   = (unsigned short*)(ws + 0x3820000);  // 48 MiB
    unsigned short* oslab = (unsigned short*)(ws + 0x6820000);  // 17408*1024*2 = 34 MiB
    unsigned short* h     = (unsigned short*)(ws + 0x8A20000);  // 17408*4096*2 = 136 MiB
    // total ≈ 287.4 MB (< proven-available ≥316.6 MB from round-2/3 BF=4096 runs)

    convx_kernel<<<NTOK * D_MODEL / 4 / 256, 256, 0, stream>>>(x, xb);
    transpose_kernel<<<dim3(D_FF / 64, D_MODEL / 64, 6), 256, 0, stream>>>(W1, W1t, D_MODEL, D_FF);
    transpose_kernel<<<dim3(D_MODEL / 64, D_FF / 64, 6), 256, 0, stream>>>(W2, W2t, D_FF, D_MODEL);
    hipMemsetAsync(cnt, 0, 512, stream);
    router_kernel<<<NTOK / 4, 256, 0, stream>>>(x, rW, logits, selpk, slotpk, cnt, list);

    // pass1: h = gelu(x @ W1^T + b1)   (M = slab rows, N = 4096, K = 1024)
    gemm8_kernel<1><<<dim3(D_FF / 256, 16, 6), 512, 0, stream>>>(
        xb, W1t, b1, D_FF, D_FF, h, cnt, list, D_MODEL);
    // pass2: oslab = h @ W2^T + b2     (M = slab rows, N = 1024, K = 4096)
    gemm8_kernel<0><<<dim3(D_MODEL / 256, 16, 6), 512, 0, stream>>>(
        h, W2t, b2, D_MODEL, D_MODEL, oslab, cnt, list, D_FF);

    pass3_kernel<<<NTOK, 256, 0, stream>>>(oslab, selpk, slotpk, cnt, gam, bet, out);
}